// Round 5
// baseline (8316.814 us; speedup 1.0000x reference)
//
#include <hip/hip_runtime.h>
#include <math.h>

// AVWDCRNN: 2-layer adaptive graph-conv GRU. B=8,T=12,N=256,Din=2,H=64,E=16.
// Round 5: ALL-F32. Diagnosis: inputs/outputs are f32 (npz sizes, f32-read
// evidence); rounds 2/3 failed because bf16 storage of precomputed W/sub/adj
// was chaos-amplified by the saturating 24-step recurrence into +-1 flips.
// Layout: ~106 MB primary tier (cur0 aliased into d_out); compact fallback
// (W recomputed in k_mm from pools) if ws_size is smaller; sentinel if tiny.

#define NF __restrict__

constexpr int N_ = 256, B_ = 8, T_ = 12, H_ = 64, E_ = 16;

__global__ void k_sentinel(float* NF out) { out[0] = 1.0e6f; }

// ---------------- adj[n][m] = softmax_m(relu(e_n . e_m)) ----------------
__global__ void k_adj(const float* NF ne, float* NF adj) {
    int n = blockIdx.x, m = threadIdx.x;   // 256 x 256
    __shared__ float en[E_];
    __shared__ float red[256];
    if (m < E_) en[m] = ne[n * E_ + m];
    __syncthreads();
    float s = 0.f;
#pragma unroll
    for (int d = 0; d < E_; d++) s += en[d] * ne[m * E_ + d];
    s = fmaxf(s, 0.f);
    red[m] = s; __syncthreads();
    for (int st = 128; st > 0; st >>= 1) { if (m < st) red[m] = fmaxf(red[m], red[m + st]); __syncthreads(); }
    float mx = red[0]; __syncthreads();
    float e = __expf(s - mx);
    red[m] = e; __syncthreads();
    for (int st = 128; st > 0; st >>= 1) { if (m < st) red[m] += red[m + st]; __syncthreads(); }
    adj[(size_t)n * N_ + m] = e / red[0];
}

// ------------- bias[n,o] = sum_d e[n,d] bp[d,o] -------------
template <int O>
__global__ void k_bias(const float* NF ne, const float* NF bp, float* NF Bout) {
    int n = blockIdx.x, o = threadIdx.x;
    float acc = 0.f;
#pragma unroll
    for (int d = 0; d < E_; d++) acc += ne[n * E_ + d] * bp[d * O + o];
    Bout[(size_t)n * O + o] = acc;
}

// ------------- W[n,j,o] = sum_d e[n,d] wp[d,j,o] (primary tier only) -------------
template <int O>
__global__ void k_wpool(const float* NF ne, const float* NF wp, float* NF W, int I2) {
    int j = blockIdx.x, n = blockIdx.y, o = threadIdx.x;   // grid (I2, 256), block O
    float acc = 0.f;
#pragma unroll
    for (int d = 0; d < E_; d++) acc += ne[n * E_ + d] * wp[((size_t)d * I2 + j) * O + o];
    W[((size_t)n * I2 + j) * O + o] = acc;
}

// ------------- sub pass 1: e[tb,i,j] = exp(-sum_h |pa[i,h]-pa[j,h]|) -------------
__global__ void k_sub_e(const float* NF pa, float* NF sub) {
    int i = blockIdx.x, tb = blockIdx.y;   // grid (256, 96); tb = t*B+b
    int t = tb / B_, b = tb % B_;
    const float* p = pa + ((size_t)b * T_ + t) * N_ * H_;
    __shared__ float rowi[H_];
    int j = threadIdx.x;                   // 256 threads
    if (j < H_) rowi[j] = p[i * H_ + j];
    __syncthreads();
    float d = 0.f;
#pragma unroll
    for (int h = 0; h < H_; h++) d += fabsf(rowi[h] - p[j * H_ + h]);
    sub[((size_t)tb * N_ + i) * N_ + j] = __expf(-d);
}

// ------------- sub pass 2: column-normalize (softmax over i, axis=1) -------------
__global__ void k_sub_norm(float* NF sub) {
    int tb = blockIdx.x, j = threadIdx.x;  // 96 blocks x 256
    float* s = sub + (size_t)tb * N_ * N_;
    float S = 0.f;
    for (int i = 0; i < N_; i++) S += s[(size_t)i * N_ + j];
    float inv = 1.f / S;
    for (int i = 0; i < N_; i++) s[(size_t)i * N_ + j] *= inv;
}

// ------------- sa = init_state[l] + pa[:,0] -------------
__global__ void k_init_sa(const float* NF ist_l, const float* NF pa, float* NF sa) {
    int idx = blockIdx.x * 256 + threadIdx.x;   // 131072 total
    int b = idx >> 14, rem = idx & 16383;       // N*H = 16384
    sa[idx] = ist_l[idx] + pa[(size_t)b * T_ * 16384 + rem];
}

// ------------- y0[b,p,i] = sum_m sub[b,p,m] * u[b,m,i] (u assembled inline) -------------
// grid 256 = b(8) x pt(32); 128 thr: i4=tid&31 (4 cols), pg=tid>>5 (2 rows each)
template <int DIN, int I, bool ZMUL>
__global__ void k_y0(const float* NF xin, int t, const float* NF sa, const float* NF zr,
                     const float* NF subt, float* NF y0) {
    int blk = blockIdx.x; int b = blk >> 5, pt = blk & 31;
    int tid = threadIdx.x; int i4 = tid & 31, pg = tid >> 5;
    const float* sb  = subt + (size_t)b * N_ * N_;
    const float* xb  = xin + ((size_t)b * T_ + t) * N_ * DIN;
    const float* sab = sa + (size_t)b * N_ * H_;
    const float* zb  = zr + (size_t)b * N_ * 128;
    __shared__ float slds[8][256];
#pragma unroll
    for (int k = 0; k < 16; k++) {
        int idx = k * 128 + tid;
        slds[idx >> 8][idx & 255] = sb[(size_t)(pt * 8 + (idx >> 8)) * N_ + (idx & 255)];
    }
    __syncthreads();
    float acc[2][4];
#pragma unroll
    for (int a = 0; a < 2; a++)
#pragma unroll
        for (int c = 0; c < 4; c++) acc[a][c] = 0.f;
    int ibase = i4 * 4;
    for (int m = 0; m < N_; m++) {
        float u[4];
#pragma unroll
        for (int c = 0; c < 4; c++) {
            int i = ibase + c;
            float v = 0.f;
            if (i < DIN) v = xb[m * DIN + i];
            else if (i < I) {
                v = sab[m * H_ + (i - DIN)];
                if (ZMUL) v *= zb[m * 128 + (i - DIN)];
            }
            u[c] = v;
        }
#pragma unroll
        for (int a = 0; a < 2; a++) {
            float sv = slds[pg * 2 + a][m];
#pragma unroll
            for (int c = 0; c < 4; c++) acc[a][c] = fmaf(sv, u[c], acc[a][c]);
        }
    }
#pragma unroll
    for (int a = 0; a < 2; a++) {
        int p = pt * 8 + pg * 2 + a;
        float* dst = y0 + ((size_t)b * N_ + p) * 128 + ibase;
#pragma unroll
        for (int c = 0; c < 4; c++) dst[c] = acc[a][c];
    }
}

// ------------- y1[b,p,i] = sum_m adj[p,m] * y0[b,m,i] -------------
__global__ void k_y1(const float* NF adj, const float* NF y0, float* NF y1) {
    int blk = blockIdx.x; int b = blk >> 5, pt = blk & 31;
    int tid = threadIdx.x; int i4 = tid & 31, pg = tid >> 5;
    __shared__ float alds[8][256];
#pragma unroll
    for (int k = 0; k < 16; k++) {
        int idx = k * 128 + tid;
        alds[idx >> 8][idx & 255] = adj[(size_t)(pt * 8 + (idx >> 8)) * N_ + (idx & 255)];
    }
    __syncthreads();
    float acc[2][4];
#pragma unroll
    for (int a = 0; a < 2; a++)
#pragma unroll
        for (int c = 0; c < 4; c++) acc[a][c] = 0.f;
    const float* yb = y0 + (size_t)b * N_ * 128;
    int ibase = i4 * 4;
    for (int m = 0; m < N_; m++) {
        float4 u = *(const float4*)(yb + (size_t)m * 128 + ibase);
#pragma unroll
        for (int a = 0; a < 2; a++) {
            float av = alds[pg * 2 + a][m];
            acc[a][0] = fmaf(av, u.x, acc[a][0]);
            acc[a][1] = fmaf(av, u.y, acc[a][1]);
            acc[a][2] = fmaf(av, u.z, acc[a][2]);
            acc[a][3] = fmaf(av, u.w, acc[a][3]);
        }
    }
#pragma unroll
    for (int a = 0; a < 2; a++) {
        int p = pt * 8 + pg * 2 + a;
        float* dst = y1 + ((size_t)b * N_ + p) * 128 + ibase;
#pragma unroll
        for (int c = 0; c < 4; c++) dst[c] = acc[a][c];
    }
}

// ------------- out[b,n,o] = act([y0;y1] @ W[n] + bias); epilogues fused -------------
// grid 256 (node n), block O. MODE 0: sigmoid -> zr. MODE 1: GRU combine.
// PRE=true: Wp is precomputed (N,2I,O). PRE=false: Wp is the pool (E,2I,O),
// W recomputed inline (compact tier).
template <int I, int O, int MODE, bool PRE>
__global__ void k_mm(const float* NF y0, const float* NF y1, const float* NF Wp,
                     const float* NF Bb, const float* NF ne, float* NF zr, float* NF sa,
                     const float* NF pa, float* NF seqout, float* NF hidout, int t) {
    int n = blockIdx.x, o = threadIdx.x;
    __shared__ float xg[8][2 * I];
    __shared__ float neS[E_];
    for (int b = 0; b < 8; b++)
        for (int j = o; j < 2 * I; j += O)
            xg[b][j] = (j < I) ? y0[((size_t)b * N_ + n) * 128 + j]
                               : y1[((size_t)b * N_ + n) * 128 + (j - I)];
    if (!PRE && o < E_) neS[o] = ne[n * E_ + o];
    __syncthreads();
    float bias = Bb[(size_t)n * O + o];
    float acc[8];
#pragma unroll
    for (int b = 0; b < 8; b++) acc[b] = bias;
    const float* Wn = PRE ? (Wp + (size_t)n * 2 * I * O + o) : (Wp + o);
    for (int j = 0; j < 2 * I; j++) {
        float w;
        if (PRE) {
            w = Wn[(size_t)j * O];
        } else {
            w = 0.f;
#pragma unroll
            for (int d = 0; d < E_; d++) w = fmaf(neS[d], Wn[((size_t)d * 2 * I + j) * O], w);
        }
#pragma unroll
        for (int b = 0; b < 8; b++) acc[b] = fmaf(xg[b][j], w, acc[b]);
    }
#pragma unroll
    for (int b = 0; b < 8; b++) {
        size_t bn = (size_t)b * N_ + n;
        if (MODE == 0) {
            zr[bn * 128 + o] = 1.f / (1.f + __expf(-acc[b]));
        } else {
            float hc = tanhf(acc[b]);
            float r = zr[bn * 128 + 64 + o];
            float s = sa[bn * 64 + o];
            float ns = hc + r * (s - hc);          // r*s + (1-r)*hc
            seqout[(((size_t)b * T_ + t) * N_ + n) * 64 + o] = ns;
            if (t < T_ - 1) sa[bn * 64 + o] = ns + pa[(((size_t)b * T_ + (t + 1)) * N_ + n) * 64 + o];
            else            hidout[bn * 64 + o] = ns;
        }
    }
}

extern "C" void kernel_launch(void* const* d_in, const int* in_sizes, int n_in,
                              void* d_out, int out_size, void* d_ws, size_t ws_size,
                              hipStream_t stream) {
    const float* x   = (const float*)d_in[0];
    const float* ist = (const float*)d_in[1];
    const float* ne  = (const float*)d_in[2];
    const float* pa  = (const float*)d_in[3];
    const float* gw0 = (const float*)d_in[4];
    const float* gb0 = (const float*)d_in[5];
    const float* uw0 = (const float*)d_in[6];
    const float* ub0 = (const float*)d_in[7];
    const float* gw1 = (const float*)d_in[8];
    const float* gb1 = (const float*)d_in[9];
    const float* uw1 = (const float*)d_in[10];
    const float* ub1 = (const float*)d_in[11];
    float* out = (float*)d_out;
    char*  base = (char*)d_ws;

    size_t off = 0;
    auto carve = [&](size_t bytes) { char* p = base + off; off += (bytes + 255) & ~(size_t)255; return p; };
    // common tier (~30 MB)
    float* adj  = (float*)carve((size_t)N_ * N_ * 4);
    float* sub  = (float*)carve((size_t)96 * N_ * N_ * 4);
    float* Bg0  = (float*)carve((size_t)N_ * 128 * 4);
    float* Bu0  = (float*)carve((size_t)N_ * 64 * 4);
    float* Bg1  = (float*)carve((size_t)N_ * 128 * 4);
    float* Bu1  = (float*)carve((size_t)N_ * 64 * 4);
    float* sa   = (float*)carve((size_t)B_ * N_ * H_ * 4);
    float* zr   = (float*)carve((size_t)B_ * N_ * 128 * 4);
    float* y0   = (float*)carve((size_t)B_ * N_ * 128 * 4);
    float* y1b  = (float*)carve((size_t)B_ * N_ * 128 * 4);
    size_t common_end = off;
    // primary tier: precomputed per-node weights (~76 MB more)
    float* Wg0  = (float*)carve((size_t)N_ * 132 * 128 * 4);
    float* Wu0  = (float*)carve((size_t)N_ * 132 * 64 * 4);
    float* Wg1  = (float*)carve((size_t)N_ * 256 * 128 * 4);
    float* Wu1  = (float*)carve((size_t)N_ * 256 * 64 * 4);
    bool pre = (off <= ws_size);
    if (!pre && common_end > ws_size) { k_sentinel<<<1, 1, 0, stream>>>(out); return; }

    float* cur_out = out;                                   // (B,T,N,H) f32
    float* hid_out = out + (size_t)B_ * T_ * N_ * H_;       // (2,B,N,H) f32
    float* cur0    = cur_out;  // layer-1 seq aliases d_out cur region (safe in-place)

    // ---- precompute ----
    k_adj<<<256, 256, 0, stream>>>(ne, adj);
    k_bias<128><<<256, 128, 0, stream>>>(ne, gb0, Bg0);
    k_bias<64><<<256, 64, 0, stream>>>(ne, ub0, Bu0);
    k_bias<128><<<256, 128, 0, stream>>>(ne, gb1, Bg1);
    k_bias<64><<<256, 64, 0, stream>>>(ne, ub1, Bu1);
    if (pre) {
        k_wpool<128><<<dim3(132, 256), 128, 0, stream>>>(ne, gw0, Wg0, 132);
        k_wpool<64><<<dim3(132, 256), 64, 0, stream>>>(ne, uw0, Wu0, 132);
        k_wpool<128><<<dim3(256, 256), 128, 0, stream>>>(ne, gw1, Wg1, 256);
        k_wpool<64><<<dim3(256, 256), 64, 0, stream>>>(ne, uw1, Wu1, 256);
    }
    k_sub_e<<<dim3(256, 96), 256, 0, stream>>>(pa, sub);
    k_sub_norm<<<96, 256, 0, stream>>>(sub);

    for (int l = 0; l < 2; l++) {
        k_init_sa<<<512, 256, 0, stream>>>(ist + (size_t)l * B_ * N_ * H_, pa, sa);
        const float* xin = (l == 0) ? x : cur0;
        float* seqout = (l == 0) ? cur0 : cur_out;
        float* hout = hid_out + (size_t)l * B_ * N_ * H_;
        for (int t = 0; t < T_; t++) {
            const float* subt = sub + (size_t)t * B_ * N_ * N_;
            if (l == 0) {
                k_y0<2, 66, false><<<256, 128, 0, stream>>>(xin, t, sa, zr, subt, y0);
                k_y1<<<256, 128, 0, stream>>>(adj, y0, y1b);
                if (pre) k_mm<66, 128, 0, true ><<<256, 128, 0, stream>>>(y0, y1b, Wg0, Bg0, ne, zr, nullptr, nullptr, nullptr, nullptr, t);
                else     k_mm<66, 128, 0, false><<<256, 128, 0, stream>>>(y0, y1b, gw0, Bg0, ne, zr, nullptr, nullptr, nullptr, nullptr, t);
                k_y0<2, 66, true><<<256, 128, 0, stream>>>(xin, t, sa, zr, subt, y0);
                k_y1<<<256, 128, 0, stream>>>(adj, y0, y1b);
                if (pre) k_mm<66, 64, 1, true ><<<256, 64, 0, stream>>>(y0, y1b, Wu0, Bu0, ne, zr, sa, pa, seqout, hout, t);
                else     k_mm<66, 64, 1, false><<<256, 64, 0, stream>>>(y0, y1b, uw0, Bu0, ne, zr, sa, pa, seqout, hout, t);
            } else {
                k_y0<64, 128, false><<<256, 128, 0, stream>>>(xin, t, sa, zr, subt, y0);
                k_y1<<<256, 128, 0, stream>>>(adj, y0, y1b);
                if (pre) k_mm<128, 128, 0, true ><<<256, 128, 0, stream>>>(y0, y1b, Wg1, Bg1, ne, zr, nullptr, nullptr, nullptr, nullptr, t);
                else     k_mm<128, 128, 0, false><<<256, 128, 0, stream>>>(y0, y1b, gw1, Bg1, ne, zr, nullptr, nullptr, nullptr, nullptr, t);
                k_y0<64, 128, true><<<256, 128, 0, stream>>>(xin, t, sa, zr, subt, y0);
                k_y1<<<256, 128, 0, stream>>>(adj, y0, y1b);
                if (pre) k_mm<128, 64, 1, true ><<<256, 64, 0, stream>>>(y0, y1b, Wu1, Bu1, ne, zr, sa, pa, seqout, hout, t);
                else     k_mm<128, 64, 1, false><<<256, 64, 0, stream>>>(y0, y1b, uw1, Bu1, ne, zr, sa, pa, seqout, hout, t);
            }
        }
    }
    (void)in_sizes; (void)n_in; (void)out_size;
}

// Round 6
// 1650.630 us; speedup vs baseline: 5.0386x; 5.0386x over previous
//
#include <hip/hip_runtime.h>
#include <math.h>

// AVWDCRNN round 6: throughput restructure (all-f32, proven correct in r5).
//  - A2[t,b] = adj @ sub[t,b] precomputed -> y0/y1 independent, one k_y2k launch.
//  - k_y2k: 32rows x 128cols x m-split-2 LDS-tiled, 4x4/thread, float4.
//  - u-assembly fused into k_mm epilogues (u1/u2 packing).
//  - W buffers shared across layers (re-pooled mid-stream): ws ~108 MB (tier A)
//    or ~83 MB (tier B: y1 = adj@y0 second pass), sentinel if tiny.

#define NF __restrict__
constexpr int N_ = 256, B_ = 8, T_ = 12, H_ = 64, E_ = 16;

__global__ void k_sentinel(float* NF out) { out[0] = 1.0e6f; }

// ---------------- adj = softmax(relu(E E^T), axis=1) ----------------
__global__ void k_adj(const float* NF ne, float* NF adj) {
    int n = blockIdx.x, m = threadIdx.x;
    __shared__ float en[E_];
    __shared__ float red[256];
    if (m < E_) en[m] = ne[n * E_ + m];
    __syncthreads();
    float s = 0.f;
#pragma unroll
    for (int d = 0; d < E_; d++) s += en[d] * ne[m * E_ + d];
    s = fmaxf(s, 0.f);
    red[m] = s; __syncthreads();
    for (int st = 128; st > 0; st >>= 1) { if (m < st) red[m] = fmaxf(red[m], red[m + st]); __syncthreads(); }
    float mx = red[0]; __syncthreads();
    float e = __expf(s - mx);
    red[m] = e; __syncthreads();
    for (int st = 128; st > 0; st >>= 1) { if (m < st) red[m] += red[m + st]; __syncthreads(); }
    adj[(size_t)n * N_ + m] = e / red[0];
}

// ------------- bias[n,o] = sum_d e[n,d] bp[d,o] -------------
template <int O>
__global__ void k_bias(const float* NF ne, const float* NF bp, float* NF Bout) {
    int n = blockIdx.x, o = threadIdx.x;
    float acc = 0.f;
#pragma unroll
    for (int d = 0; d < E_; d++) acc += ne[n * E_ + d] * bp[d * O + o];
    Bout[(size_t)n * O + o] = acc;
}

// ------------- W[n,j,o] = sum_d e[n,d] wp[d,j,o], float4 flat -------------
__global__ void k_wpool(const float* NF ne, const float* NF wp, float* NF W,
                        int I2, int O4, int total4) {
    int idx4 = blockIdx.x * 256 + threadIdx.x;
    if (idx4 >= total4) return;
    int o4 = idx4 % O4; int rem = idx4 / O4; int j = rem % I2; int n = rem / I2;
    const float* nrow = ne + n * E_;
    float ax = 0.f, ay = 0.f, az = 0.f, aw = 0.f;
#pragma unroll
    for (int d = 0; d < E_; d++) {
        float e = nrow[d];
        const float4 w = *(const float4*)&wp[(((size_t)d * I2 + j) * O4 + o4) * 4];
        ax = fmaf(e, w.x, ax); ay = fmaf(e, w.y, ay); az = fmaf(e, w.z, az); aw = fmaf(e, w.w, aw);
    }
    float4 r; r.x = ax; r.y = ay; r.z = az; r.w = aw;
    *(float4*)&W[(size_t)idx4 * 4] = r;
}

// ------------- sub pass 1: e[tb,i,j] = exp(-L1(pa_i, pa_j)) -------------
__global__ void k_sub_e(const float* NF pa, float* NF sub) {
    int i = blockIdx.x, tb = blockIdx.y;   // tb = t*B+b
    int t = tb / B_, b = tb % B_;
    const float* p = pa + ((size_t)b * T_ + t) * N_ * H_;
    __shared__ float rowi[H_];
    int j = threadIdx.x;
    if (j < H_) rowi[j] = p[i * H_ + j];
    __syncthreads();
    float d = 0.f;
#pragma unroll
    for (int h = 0; h < H_; h++) d += fabsf(rowi[h] - p[j * H_ + h]);
    sub[((size_t)tb * N_ + i) * N_ + j] = __expf(-d);
}

// ------------- sub pass 2: column softmax normalize -------------
__global__ void k_sub_norm(float* NF sub) {
    int tb = blockIdx.x, tid = threadIdx.x;   // 96 x 1024
    int j = tid & 255, q = tid >> 8;          // 4 row-groups of 64
    float* s = sub + (size_t)tb * N_ * N_;
    __shared__ float red[4][256];
    float S = 0.f;
    for (int i = q * 64; i < q * 64 + 64; ++i) S += s[(size_t)i * N_ + j];
    red[q][j] = S; __syncthreads();
    float inv = 1.f / (red[0][j] + red[1][j] + red[2][j] + red[3][j]);
    for (int i = q * 64; i < q * 64 + 64; ++i) s[(size_t)i * N_ + j] *= inv;
}

// ------------- A2[tb] = adj @ sub[tb]  (32r x 128c tiles) -------------
__global__ __launch_bounds__(256) void k_a2(const float* NF adj, const float* NF sub, float* NF a2) {
    int bx = blockIdx.x; int rt = bx & 7, ch = bx >> 3;   // grid (16, 96)
    int tb = blockIdx.y;
    const float* U = sub + (size_t)tb * N_ * N_;
    float* dst = a2 + (size_t)tb * N_ * N_;
    __shared__ float SL[64][36];
    __shared__ float UL[64][128];
    int tid = threadIdx.x, cg = tid & 31, rg = tid >> 5;
    float acc[4][4];
#pragma unroll
    for (int a = 0; a < 4; a++)
#pragma unroll
        for (int c = 0; c < 4; c++) acc[a][c] = 0.f;
    int p0 = rt * 32, c0 = ch * 128;
    for (int mc = 0; mc < 4; ++mc) {
        int mb = mc * 64;
        for (int idx = tid; idx < 2048; idx += 256) {
            int mm = idx & 63, r = idx >> 6;
            SL[mm][r] = adj[(size_t)(p0 + r) * N_ + mb + mm];
        }
#pragma unroll
        for (int q = 0; q < 8; ++q) {
            int i4 = q * 256 + tid; int row = i4 >> 5, c4 = i4 & 31;
            *(float4*)&UL[row][c4 * 4] = *(const float4*)&U[(size_t)(mb + row) * N_ + c0 + c4 * 4];
        }
        __syncthreads();
        for (int mm = 0; mm < 64; ++mm) {
            float4 s4 = *(const float4*)&SL[mm][rg * 4];
            float4 u4 = *(const float4*)&UL[mm][cg * 4];
            float sv[4] = { s4.x, s4.y, s4.z, s4.w };
            float uv[4] = { u4.x, u4.y, u4.z, u4.w };
#pragma unroll
            for (int a = 0; a < 4; a++)
#pragma unroll
                for (int c = 0; c < 4; c++) acc[a][c] = fmaf(sv[a], uv[c], acc[a][c]);
        }
        __syncthreads();
    }
#pragma unroll
    for (int a = 0; a < 4; a++) {
        float4 v; v.x = acc[a][0]; v.y = acc[a][1]; v.z = acc[a][2]; v.w = acc[a][3];
        *(float4*)&dst[(size_t)(p0 + rg * 4 + a) * N_ + c0 + cg * 4] = v;
    }
}

// ------------- y partials: y[b,k] = S_k[b] @ u[b]  (both k, m-split 2) -------------
// grid 256: pt(8 x 32rows) | ms(2) | k(2) | b(8). yA: ms=0 partial, yB: ms=1.
__global__ __launch_bounds__(256) void k_y2k(const float* NF sub_t, const float* NF a2_t,
                                             const float* NF u, float* NF yA, float* NF yB) {
    int bx = blockIdx.x;
    int pt = bx & 7, ms = (bx >> 3) & 1, k = (bx >> 4) & 1, b = bx >> 5;
    const float* S = (k ? a2_t : sub_t) + (size_t)b * N_ * N_;
    const float* ub = u + (size_t)b * N_ * 128;
    float* dst = (ms ? yB : yA) + (((size_t)b * 2 + k) * N_ + pt * 32) * 128;
    __shared__ float SL[64][36];
    __shared__ float UL[64][128];
    int tid = threadIdx.x, cg = tid & 31, rg = tid >> 5;
    float acc[4][4];
#pragma unroll
    for (int a = 0; a < 4; a++)
#pragma unroll
        for (int c = 0; c < 4; c++) acc[a][c] = 0.f;
    int p0 = pt * 32, m0 = ms * 128;
    for (int mc = 0; mc < 2; ++mc) {
        int mb = m0 + mc * 64;
        for (int idx = tid; idx < 2048; idx += 256) {
            int mm = idx & 63, r = idx >> 6;
            SL[mm][r] = S[(size_t)(p0 + r) * N_ + mb + mm];
        }
#pragma unroll
        for (int q = 0; q < 8; ++q) {
            int i4 = q * 256 + tid; int row = i4 >> 5, c4 = i4 & 31;
            *(float4*)&UL[row][c4 * 4] = *(const float4*)&ub[(size_t)(mb + row) * 128 + c4 * 4];
        }
        __syncthreads();
        for (int mm = 0; mm < 64; ++mm) {
            float4 s4 = *(const float4*)&SL[mm][rg * 4];
            float4 u4 = *(const float4*)&UL[mm][cg * 4];
            float sv[4] = { s4.x, s4.y, s4.z, s4.w };
            float uv[4] = { u4.x, u4.y, u4.z, u4.w };
#pragma unroll
            for (int a = 0; a < 4; a++)
#pragma unroll
                for (int c = 0; c < 4; c++) acc[a][c] = fmaf(sv[a], uv[c], acc[a][c]);
        }
        __syncthreads();
    }
#pragma unroll
    for (int a = 0; a < 4; a++) {
        float4 v; v.x = acc[a][0]; v.y = acc[a][1]; v.z = acc[a][2]; v.w = acc[a][3];
        *(float4*)&dst[(size_t)(rg * 4 + a) * 128 + cg * 4] = v;
    }
}

// ------------- tier-B single-S y kernel (grid 128: pt|ms|b), optional u-add -------------
__global__ __launch_bounds__(256) void k_y1k(const float* NF S, long sbstride,
                                             const float* NF u, const float* NF uadd, long ubstride,
                                             float* NF yA, float* NF yB, int kslot) {
    int bx = blockIdx.x;
    int pt = bx & 7, ms = (bx >> 3) & 1, b = bx >> 4;
    const float* Sb = S + (size_t)b * sbstride;
    const float* ub = u + (size_t)b * ubstride;
    const float* ub2 = uadd ? uadd + (size_t)b * ubstride : nullptr;
    float* dst = (ms ? yB : yA) + (((size_t)b * 2 + kslot) * N_ + pt * 32) * 128;
    __shared__ float SL[64][36];
    __shared__ float UL[64][128];
    int tid = threadIdx.x, cg = tid & 31, rg = tid >> 5;
    float acc[4][4];
#pragma unroll
    for (int a = 0; a < 4; a++)
#pragma unroll
        for (int c = 0; c < 4; c++) acc[a][c] = 0.f;
    int p0 = pt * 32, m0 = ms * 128;
    for (int mc = 0; mc < 2; ++mc) {
        int mb = m0 + mc * 64;
        for (int idx = tid; idx < 2048; idx += 256) {
            int mm = idx & 63, r = idx >> 6;
            SL[mm][r] = Sb[(size_t)(p0 + r) * N_ + mb + mm];
        }
#pragma unroll
        for (int q = 0; q < 8; ++q) {
            int i4 = q * 256 + tid; int row = i4 >> 5, c4 = i4 & 31;
            float4 v = *(const float4*)&ub[(size_t)(mb + row) * 128 + c4 * 4];
            if (ub2) {
                float4 w = *(const float4*)&ub2[(size_t)(mb + row) * 128 + c4 * 4];
                v.x += w.x; v.y += w.y; v.z += w.z; v.w += w.w;
            }
            *(float4*)&UL[row][c4 * 4] = v;
        }
        __syncthreads();
        for (int mm = 0; mm < 64; ++mm) {
            float4 s4 = *(const float4*)&SL[mm][rg * 4];
            float4 u4 = *(const float4*)&UL[mm][cg * 4];
            float sv[4] = { s4.x, s4.y, s4.z, s4.w };
            float uv[4] = { u4.x, u4.y, u4.z, u4.w };
#pragma unroll
            for (int a = 0; a < 4; a++)
#pragma unroll
                for (int c = 0; c < 4; c++) acc[a][c] = fmaf(sv[a], uv[c], acc[a][c]);
        }
        __syncthreads();
    }
#pragma unroll
    for (int a = 0; a < 4; a++) {
        float4 v; v.x = acc[a][0]; v.y = acc[a][1]; v.z = acc[a][2]; v.w = acc[a][3];
        *(float4*)&dst[(size_t)(rg * 4 + a) * 128 + cg * 4] = v;
    }
}

// ------------- init u1 = [x_0 | ist+pa_0 | 0], u2 = 0 -------------
template <int DIN, int I>
__global__ void k_init_u(const float* NF xin, const float* NF ist_l, const float* NF pa,
                         float* NF u1, float* NF u2) {
    int idx = blockIdx.x * 256 + threadIdx.x;      // 8*256*128
    int c = idx & 127, n = (idx >> 7) & 255, b = idx >> 15;
    float v = 0.f;
    if (c < DIN) v = xin[((size_t)b * T_) * N_ * DIN + n * DIN + c];
    else if (c < I) v = ist_l[((size_t)b * N_ + n) * H_ + (c - DIN)]
                      + pa[((size_t)b * T_) * N_ * H_ + n * H_ + (c - DIN)];
    u1[idx] = v;
    u2[idx] = 0.f;
}

// ------------- mm + fused GRU epilogues -------------
// grid 256(n) x 256 thr: o = tid%O, bg = tid/O; BPG b's per thread.
// MODE 0: z,r; writes u2=[x_t | z*sa], rbuf=r.  MODE 1: GRU combine; writes seq,
// u1_next=[x_{t+1} | ns+pa_{t+1}] (or hid at t=T-1).
template <int DIN, int I, int O, int MODE>
__global__ __launch_bounds__(256) void k_mm(const float* NF yA, const float* NF yB,
                                            const float* NF W, const float* NF Bb,
                                            float* NF u1, float* NF u2, float* NF rbuf,
                                            const float* NF xin, const float* NF pa,
                                            float* NF seqout, float* NF hidout, int t) {
    constexpr int NB = 256 / O;
    constexpr int BPG = 8 / NB;
    int n = blockIdx.x, tid = threadIdx.x;
    int o = tid % O, bg = tid / O;
    __shared__ float xg[2 * I][12];
    for (int idx = tid; idx < 8 * 2 * I; idx += 256) {
        int b = idx / (2 * I), j = idx % (2 * I);
        int k = (j < I) ? 0 : 1;
        int jj = (j < I) ? j : j - I;
        size_t src = (((size_t)b * 2 + k) * N_ + n) * 128 + jj;
        xg[j][b] = yA[src] + yB[src];
    }
    __syncthreads();
    float bias = Bb[(size_t)n * O + o];
    float acc[BPG];
#pragma unroll
    for (int q = 0; q < BPG; ++q) acc[q] = bias;
    const float* Wn = W + ((size_t)n * 2 * I) * O + o;
#pragma unroll 4
    for (int j = 0; j < 2 * I; ++j) {
        float w = Wn[(size_t)j * O];
        if (BPG == 4) {
            float4 xb = *(const float4*)&xg[j][bg * 4];
            acc[0] = fmaf(xb.x, w, acc[0]);
            acc[1] = fmaf(xb.y, w, acc[1]);
            acc[2] = fmaf(xb.z, w, acc[2]);
            acc[3] = fmaf(xb.w, w, acc[3]);
        } else {
            float2 xb = *(const float2*)&xg[j][bg * 2];
            acc[0] = fmaf(xb.x, w, acc[0]);
            acc[1] = fmaf(xb.y, w, acc[1]);
        }
    }
#pragma unroll
    for (int q = 0; q < BPG; ++q) {
        int b = bg * BPG + q;
        size_t bn = (size_t)b * N_ + n;
        if (MODE == 0) {
            float v = 1.f / (1.f + __expf(-acc[q]));
            if (o < H_) u2[bn * 128 + DIN + o] = v * u1[bn * 128 + DIN + o];   // z * sa
            else        rbuf[bn * H_ + (o - H_)] = v;                          // r
            if (o < DIN) u2[bn * 128 + o] = xin[((size_t)b * T_ + t) * N_ * DIN + n * DIN + o];
        } else {
            float hc = tanhf(acc[q]);
            float r = rbuf[bn * H_ + o];
            float s = u1[bn * 128 + DIN + o];
            float ns = hc + r * (s - hc);
            seqout[(((size_t)b * T_ + t) * N_ + n) * H_ + o] = ns;
            if (t < T_ - 1) {
                u1[bn * 128 + DIN + o] = ns + pa[(((size_t)b * T_ + (t + 1)) * N_ + n) * H_ + o];
                if (o < DIN) u1[bn * 128 + o] = xin[((size_t)b * T_ + (t + 1)) * N_ * DIN + n * DIN + o];
            } else {
                hidout[bn * H_ + o] = ns;
            }
        }
    }
}

extern "C" void kernel_launch(void* const* d_in, const int* in_sizes, int n_in,
                              void* d_out, int out_size, void* d_ws, size_t ws_size,
                              hipStream_t stream) {
    const float* x   = (const float*)d_in[0];
    const float* ist = (const float*)d_in[1];
    const float* ne  = (const float*)d_in[2];
    const float* pa  = (const float*)d_in[3];
    const float* gw0 = (const float*)d_in[4];
    const float* gb0 = (const float*)d_in[5];
    const float* uw0 = (const float*)d_in[6];
    const float* ub0 = (const float*)d_in[7];
    const float* gw1 = (const float*)d_in[8];
    const float* gb1 = (const float*)d_in[9];
    const float* uw1 = (const float*)d_in[10];
    const float* ub1 = (const float*)d_in[11];
    float* out = (float*)d_out;
    char*  base = (char*)d_ws;

    size_t off = 0;
    auto carve = [&](size_t bytes) { char* p = base + off; off += (bytes + 255) & ~(size_t)255; return p; };
    float* adj  = (float*)carve((size_t)N_ * N_ * 4);
    float* sub  = (float*)carve((size_t)96 * N_ * N_ * 4);
    float* Wg   = (float*)carve((size_t)N_ * 256 * 128 * 4);   // shared: Wg0(132) / Wg1(256)
    float* Wu   = (float*)carve((size_t)N_ * 256 * 64 * 4);    // shared: Wu0 / Wu1
    float* Bg0  = (float*)carve((size_t)N_ * 128 * 4);
    float* Bu0  = (float*)carve((size_t)N_ * 64 * 4);
    float* Bg1  = (float*)carve((size_t)N_ * 128 * 4);
    float* Bu1  = (float*)carve((size_t)N_ * 64 * 4);
    float* u1   = (float*)carve((size_t)B_ * N_ * 128 * 4);
    float* u2   = (float*)carve((size_t)B_ * N_ * 128 * 4);
    float* yA   = (float*)carve((size_t)B_ * 2 * N_ * 128 * 4);
    float* yB   = (float*)carve((size_t)B_ * 2 * N_ * 128 * 4);
    float* rbuf = (float*)carve((size_t)B_ * N_ * H_ * 4);
    size_t base_end = off;
    float* A2   = (float*)carve((size_t)96 * N_ * N_ * 4);     // tier A only
    bool tierA = (off <= ws_size);
    if (!tierA && base_end > ws_size) { k_sentinel<<<1, 1, 0, stream>>>(out); return; }

    float* cur_out = out;                                   // (B,T,N,H)
    float* hid_out = out + (size_t)B_ * T_ * N_ * H_;       // (2,B,N,H)
    float* cur0    = cur_out;                               // layer0 seq aliases d_out

    // ---- time-invariant precompute ----
    k_adj<<<256, 256, 0, stream>>>(ne, adj);
    k_bias<128><<<256, 128, 0, stream>>>(ne, gb0, Bg0);
    k_bias<64><<<256, 64, 0, stream>>>(ne, ub0, Bu0);
    k_bias<128><<<256, 128, 0, stream>>>(ne, gb1, Bg1);
    k_bias<64><<<256, 64, 0, stream>>>(ne, ub1, Bu1);
    k_sub_e<<<dim3(256, 96), 256, 0, stream>>>(pa, sub);
    k_sub_norm<<<96, 1024, 0, stream>>>(sub);
    if (tierA) k_a2<<<dim3(16, 96), 256, 0, stream>>>(adj, sub, A2);

    for (int l = 0; l < 2; l++) {
        // per-layer weight pooling into the shared W buffers
        if (l == 0) {
            int t4g = N_ * 132 * 128 / 4, t4u = N_ * 132 * 64 / 4;
            k_wpool<<<(t4g + 255) / 256, 256, 0, stream>>>(ne, gw0, Wg, 132, 32, t4g);
            k_wpool<<<(t4u + 255) / 256, 256, 0, stream>>>(ne, uw0, Wu, 132, 16, t4u);
        } else {
            int t4g = N_ * 256 * 128 / 4, t4u = N_ * 256 * 64 / 4;
            k_wpool<<<(t4g + 255) / 256, 256, 0, stream>>>(ne, gw1, Wg, 256, 32, t4g);
            k_wpool<<<(t4u + 255) / 256, 256, 0, stream>>>(ne, uw1, Wu, 256, 16, t4u);
        }
        const float* xin = (l == 0) ? x : cur0;
        const float* ist_l = ist + (size_t)l * B_ * N_ * H_;
        float* seqout = (l == 0) ? cur0 : cur_out;
        float* hout = hid_out + (size_t)l * B_ * N_ * H_;
        if (l == 0) k_init_u<2, 66><<<1024, 256, 0, stream>>>(xin, ist_l, pa, u1, u2);
        else        k_init_u<64, 128><<<1024, 256, 0, stream>>>(xin, ist_l, pa, u1, u2);

        for (int t = 0; t < T_; t++) {
            const float* sub_t = sub + (size_t)t * B_ * N_ * N_;
            const float* a2_t  = A2  + (size_t)t * B_ * N_ * N_;
            // gate y
            if (tierA) {
                k_y2k<<<256, 256, 0, stream>>>(sub_t, a2_t, u1, yA, yB);
            } else {
                k_y1k<<<128, 256, 0, stream>>>(sub_t, (long)N_ * N_, u1, nullptr, (long)N_ * 128, yA, yB, 0);
                k_y1k<<<128, 256, 0, stream>>>(adj, 0L, yA, yB, (long)2 * N_ * 128, yA, yB, 1);
            }
            if (l == 0) k_mm<2, 66, 128, 0><<<256, 256, 0, stream>>>(yA, yB, Wg, Bg0, u1, u2, rbuf, xin, pa, nullptr, nullptr, t);
            else        k_mm<64, 128, 128, 0><<<256, 256, 0, stream>>>(yA, yB, Wg, Bg1, u1, u2, rbuf, xin, pa, nullptr, nullptr, t);
            // update y
            if (tierA) {
                k_y2k<<<256, 256, 0, stream>>>(sub_t, a2_t, u2, yA, yB);
            } else {
                k_y1k<<<128, 256, 0, stream>>>(sub_t, (long)N_ * N_, u2, nullptr, (long)N_ * 128, yA, yB, 0);
                k_y1k<<<128, 256, 0, stream>>>(adj, 0L, yA, yB, (long)2 * N_ * 128, yA, yB, 1);
            }
            if (l == 0) k_mm<2, 66, 64, 1><<<256, 256, 0, stream>>>(yA, yB, Wu, Bu0, u1, u2, rbuf, xin, pa, seqout, hout, t);
            else        k_mm<64, 128, 64, 1><<<256, 256, 0, stream>>>(yA, yB, Wu, Bu1, u1, u2, rbuf, xin, pa, seqout, hout, t);
        }
    }
    (void)in_sizes; (void)n_in; (void)out_size;
}

// Round 7
// 1537.034 us; speedup vs baseline: 5.4110x; 1.0739x over previous
//
#include <hip/hip_runtime.h>
#include <math.h>

// AVWDCRNN round 7 (all-f32, correct since r5; r6=1651us).
//  - k_sub_t: GEMM-tiled distance matrix (was 187us uncoalesced -> ~10us).
//  - softmax fold: store raw E=exp(-d) + inv colsum vector; y staging multiplies u by inv.
//  - k_y: 8x8 register tiles, transposed-S LDS, b64 u-reads, 8 m-split slots.
//  - Y0X: l0 x-part (2 cols) precomputed for all t -> l0 y is 64-col.
//  - tier: A2=adj@E precomputed if ws>=122MB (4 launches/step) else serial y0->y1.

#define NF __restrict__
constexpr int N_ = 256, B_ = 8, T_ = 12, H_ = 64, E_ = 16;
constexpr int MS_ = 8;   // m-split partial slots

__global__ void k_sentinel(float* NF out) { out[0] = 1.0e6f; }

// ---------------- adj = softmax(relu(ne ne^T), axis=1) ----------------
__global__ void k_adj(const float* NF ne, float* NF adj) {
    int n = blockIdx.x, m = threadIdx.x;
    __shared__ float en[E_];
    __shared__ float red[256];
    if (m < E_) en[m] = ne[n * E_ + m];
    __syncthreads();
    float s = 0.f;
#pragma unroll
    for (int d = 0; d < E_; d++) s += en[d] * ne[m * E_ + d];
    s = fmaxf(s, 0.f);
    red[m] = s; __syncthreads();
    for (int st = 128; st > 0; st >>= 1) { if (m < st) red[m] = fmaxf(red[m], red[m + st]); __syncthreads(); }
    float mx = red[0]; __syncthreads();
    float e = __expf(s - mx);
    red[m] = e; __syncthreads();
    for (int st = 128; st > 0; st >>= 1) { if (m < st) red[m] += red[m + st]; __syncthreads(); }
    adj[(size_t)n * N_ + m] = e / red[0];
}

// ------------- bias[n,o] = sum_d e[n,d] bp[d,o] -------------
template <int O>
__global__ void k_bias(const float* NF ne, const float* NF bp, float* NF Bout) {
    int n = blockIdx.x, o = threadIdx.x;
    float acc = 0.f;
#pragma unroll
    for (int d = 0; d < E_; d++) acc += ne[n * E_ + d] * bp[d * O + o];
    Bout[(size_t)n * O + o] = acc;
}

// ------------- W[n,j,o] = sum_d e[n,d] wp[d,j,o], float4 flat -------------
__global__ void k_wpool(const float* NF ne, const float* NF wp, float* NF W,
                        int I2, int O4, int total4) {
    int idx4 = blockIdx.x * 256 + threadIdx.x;
    if (idx4 >= total4) return;
    int o4 = idx4 % O4; int rem = idx4 / O4; int j = rem % I2; int n = rem / I2;
    const float* nrow = ne + n * E_;
    float ax = 0.f, ay = 0.f, az = 0.f, aw = 0.f;
#pragma unroll
    for (int d = 0; d < E_; d++) {
        float e = nrow[d];
        const float4 w = *(const float4*)&wp[(((size_t)d * I2 + j) * O4 + o4) * 4];
        ax = fmaf(e, w.x, ax); ay = fmaf(e, w.y, ay); az = fmaf(e, w.z, az); aw = fmaf(e, w.w, aw);
    }
    float4 r; r.x = ax; r.y = ay; r.z = az; r.w = aw;
    *(float4*)&W[(size_t)idx4 * 4] = r;
}

// ------------- E[tb,i,j] = exp(-L1(pa_i, pa_j)) ; tiled 64x64 -------------
__global__ __launch_bounds__(256) void k_sub_t(const float* NF pa, float* NF Ebuf) {
    int bx = blockIdx.x, tb = blockIdx.y;    // grid (16, 96)
    int it = bx & 3, jt = bx >> 2;
    int t = tb / B_, b = tb % B_;
    const float* p = pa + ((size_t)b * T_ + t) * N_ * H_;
    __shared__ float piT[64][64];
    __shared__ float pjT[64][64];
    int tid = threadIdx.x;
    int i0 = it * 64, j0 = jt * 64;
#pragma unroll
    for (int q = 0; q < 4; q++) {
        int idx = q * 256 + tid; int hq = idx & 15, i = idx >> 4;
        float4 v = *(const float4*)&p[(size_t)(i0 + i) * 64 + hq * 4];
        piT[hq * 4 + 0][i] = v.x; piT[hq * 4 + 1][i] = v.y; piT[hq * 4 + 2][i] = v.z; piT[hq * 4 + 3][i] = v.w;
        float4 w = *(const float4*)&p[(size_t)(j0 + i) * 64 + hq * 4];
        pjT[hq * 4 + 0][i] = w.x; pjT[hq * 4 + 1][i] = w.y; pjT[hq * 4 + 2][i] = w.z; pjT[hq * 4 + 3][i] = w.w;
    }
    __syncthreads();
    int jg = tid & 15, ig = tid >> 4;
    float acc[4][4];
#pragma unroll
    for (int a = 0; a < 4; a++)
#pragma unroll
        for (int c = 0; c < 4; c++) acc[a][c] = 0.f;
    for (int h = 0; h < 64; h++) {
        float4 a4 = *(const float4*)&piT[h][ig * 4];
        float4 b4 = *(const float4*)&pjT[h][jg * 4];
        float av[4] = { a4.x, a4.y, a4.z, a4.w };
        float bv[4] = { b4.x, b4.y, b4.z, b4.w };
#pragma unroll
        for (int a = 0; a < 4; a++)
#pragma unroll
            for (int c = 0; c < 4; c++) acc[a][c] += fabsf(av[a] - bv[c]);
    }
    float* dst = Ebuf + (size_t)tb * N_ * N_;
#pragma unroll
    for (int a = 0; a < 4; a++) {
        float4 o; o.x = __expf(-acc[a][0]); o.y = __expf(-acc[a][1]);
        o.z = __expf(-acc[a][2]); o.w = __expf(-acc[a][3]);
        *(float4*)&dst[(size_t)(i0 + ig * 4 + a) * N_ + j0 + jg * 4] = o;
    }
}

// ------------- inv[tb,j] = 1 / sum_i E[tb,i,j] -------------
__global__ void k_csum(const float* NF Ebuf, float* NF inv) {
    int tb = blockIdx.x, j = threadIdx.x;
    const float* e = Ebuf + (size_t)tb * N_ * N_;
    float S = 0.f;
    for (int i = 0; i < N_; i++) S += e[(size_t)i * N_ + j];
    inv[tb * N_ + j] = 1.f / S;
}

// ------------- generic tiled GEMM: out = S @ (u [*inv | slot-sum]) -------------
// grid (rt, bk, ms). 256 thr: cg=tid%CG (8 cols each), rg=tid/CG (RPT rows each).
template <int ROWS, int COLS, int MCH, int NCH, bool USUM, bool INV>
__global__ __launch_bounds__(256) void k_y(
    const float* NF s0, const float* NF s1, long sbstr,
    const float* NF u0, long ubstr, const float* NF invt,
    float* NF outb, long out_bk, long SS, int kdim2, int kfix) {
    constexpr int CG = COLS / 8;
    constexpr int RG = 256 / CG;
    constexpr int RPT = ROWS / RG;
    __shared__ float SLT[MCH][ROWS];
    __shared__ float UL[MCH][COLS];
    int tid = threadIdx.x, cg = tid % CG, rg = tid / CG;
    int rt = blockIdx.x, bk = blockIdx.y, ms = blockIdx.z;
    int kk = kdim2 ? (bk & 1) : kfix;
    int b  = kdim2 ? (bk >> 1) : bk;
    const float* S = (kk ? s1 : s0) + (size_t)b * sbstr;
    const float* U = u0 + (size_t)b * ubstr;
    const float* ip = INV ? (invt + b * N_) : nullptr;
    int r0 = rt * ROWS;
    int mB = ms * MCH * NCH;
    float acc[RPT][8];
#pragma unroll
    for (int r = 0; r < RPT; r++)
#pragma unroll
        for (int c = 0; c < 8; c++) acc[r][c] = 0.f;
    for (int ch = 0; ch < NCH; ++ch) {
        int m0 = mB + ch * MCH;
        // stage S^T (SLT[mm][r] = S[r0+r][m0+mm])
#pragma unroll
        for (int q = 0; q < ROWS * MCH / 4 / 256; q++) {
            int idx = q * 256 + tid; int mq = idx % (MCH / 4), r = idx / (MCH / 4);
            float4 v = *(const float4*)&S[(size_t)(r0 + r) * N_ + m0 + mq * 4];
            SLT[mq * 4 + 0][r] = v.x; SLT[mq * 4 + 1][r] = v.y;
            SLT[mq * 4 + 2][r] = v.z; SLT[mq * 4 + 3][r] = v.w;
        }
        // stage U (optionally * inv[m] or slot-summed)
#pragma unroll
        for (int q = 0; q < MCH * COLS / 4 / 256; q++) {
            int idx = q * 256 + tid; int c4 = idx % (COLS / 4), mm = idx / (COLS / 4);
            const float* up = &U[(size_t)(m0 + mm) * COLS + c4 * 4];
            float4 v = *(const float4*)up;
            if (USUM) {
                for (int s = 1; s < MS_; s++) {
                    float4 w = *(const float4*)&up[(size_t)s * SS];
                    v.x += w.x; v.y += w.y; v.z += w.z; v.w += w.w;
                }
            } else if (INV) {
                float iv = ip[m0 + mm];
                v.x *= iv; v.y *= iv; v.z *= iv; v.w *= iv;
            }
            *(float4*)&UL[mm][c4 * 4] = v;
        }
        __syncthreads();
        for (int mm = 0; mm < MCH; mm++) {
            float sv[8];
            { float4 a = *(const float4*)&SLT[mm][rg * RPT];
              sv[0] = a.x; sv[1] = a.y; sv[2] = a.z; sv[3] = a.w;
              if (RPT == 8) { float4 b2 = *(const float4*)&SLT[mm][rg * RPT + 4];
                  sv[4] = b2.x; sv[5] = b2.y; sv[6] = b2.z; sv[7] = b2.w; } }
            float2 uv[4];
#pragma unroll
            for (int uu = 0; uu < 4; uu++) uv[uu] = *(const float2*)&UL[mm][cg * 2 + uu * (COLS / 4)];
#pragma unroll
            for (int r = 0; r < RPT; r++) {
#pragma unroll
                for (int uu = 0; uu < 4; uu++) {
                    acc[r][uu * 2]     = fmaf(sv[r], uv[uu].x, acc[r][uu * 2]);
                    acc[r][uu * 2 + 1] = fmaf(sv[r], uv[uu].y, acc[r][uu * 2 + 1]);
                }
            }
        }
        if (ch + 1 < NCH) __syncthreads();
    }
    float* ob = outb + (size_t)ms * SS + (size_t)bk * out_bk;
#pragma unroll
    for (int r = 0; r < RPT; r++) {
        size_t rowoff = (size_t)(r0 + rg * RPT + r) * COLS;
#pragma unroll
        for (int uu = 0; uu < 4; uu++) {
            float2 o; o.x = acc[r][uu * 2]; o.y = acc[r][uu * 2 + 1];
            *(float2*)&ob[rowoff + cg * 2 + uu * (COLS / 4)] = o;
        }
    }
}

// ------------- Y0X[tb,k,n,0:2] = S_k @ (x * inv) -------------
__global__ void k_y0xa(const float* NF s0, const float* NF s1, const float* NF inv,
                       const float* NF x, float* NF y0x, int kdim2) {
    int tb = blockIdx.x, kk = kdim2 ? blockIdx.y : 0;
    int t = tb / B_, b = tb % B_;
    const float* S = (kk ? s1 : s0) + (size_t)tb * N_ * N_;
    __shared__ float xw[256][2];
    int n = threadIdx.x;
    { float iv = inv[tb * N_ + n];
      xw[n][0] = x[(((size_t)b * T_ + t) * N_ + n) * 2 + 0] * iv;
      xw[n][1] = x[(((size_t)b * T_ + t) * N_ + n) * 2 + 1] * iv; }
    __syncthreads();
    float a0 = 0.f, a1 = 0.f;
    for (int m = 0; m < N_; m++) {
        float s = S[(size_t)n * N_ + m];
        a0 = fmaf(s, xw[m][0], a0); a1 = fmaf(s, xw[m][1], a1);
    }
    y0x[(((size_t)tb * 2 + kk) * N_ + n) * 2 + 0] = a0;
    y0x[(((size_t)tb * 2 + kk) * N_ + n) * 2 + 1] = a1;
}

// serial tier: Y0X[k=1] = adj @ Y0X[k=0]
__global__ void k_y0xb(const float* NF adj, float* NF y0x) {
    int tb = blockIdx.x, n = threadIdx.x;
    __shared__ float xk[256][2];
    xk[n][0] = y0x[(((size_t)tb * 2 + 0) * N_ + n) * 2 + 0];
    xk[n][1] = y0x[(((size_t)tb * 2 + 0) * N_ + n) * 2 + 1];
    __syncthreads();
    float a0 = 0.f, a1 = 0.f;
    for (int m = 0; m < N_; m++) {
        float s = adj[(size_t)n * N_ + m];
        a0 = fmaf(s, xk[m][0], a0); a1 = fmaf(s, xk[m][1], a1);
    }
    y0x[(((size_t)tb * 2 + 1) * N_ + n) * 2 + 0] = a0;
    y0x[(((size_t)tb * 2 + 1) * N_ + n) * 2 + 1] = a1;
}

// ------------- u init -------------
__global__ void k_init0(const float* NF ist, const float* NF pa, float* NF u1) {
    int idx = blockIdx.x * 256 + threadIdx.x;   // 131072
    int b = idx >> 14, rem = idx & 16383;
    u1[idx] = ist[idx] + pa[(size_t)b * T_ * 16384 + rem];
}
__global__ void k_init1(const float* NF cur0, const float* NF ist1, const float* NF pa, float* NF u1) {
    int idx = blockIdx.x * 256 + threadIdx.x;   // 262144
    int c = idx & 127, n = (idx >> 7) & 255, b = idx >> 15;
    float v;
    if (c < 64) v = cur0[(((size_t)b * T_) * N_ + n) * 64 + c];
    else v = ist1[((size_t)b * N_ + n) * 64 + (c - 64)] + pa[(((size_t)b * T_) * N_ + n) * 64 + (c - 64)];
    u1[idx] = v;
}

// ------------- mm + fused GRU epilogues (sums MS_ slots; l0 x-part from Y0X) -------------
template <int I, int O, int MODE, int UST, bool YX>
__global__ __launch_bounds__(256) void k_mm(
    const float* NF ybuf, long slotSS, const float* NF y0x,
    const float* NF W, const float* NF Bb,
    float* NF u1, float* NF u2, float* NF rbuf,
    const float* NF xin, const float* NF pa,
    float* NF seqout, float* NF hidout, int t) {
    constexpr int COLS = YX ? 64 : 128;
    constexpr int JX = YX ? 2 : 0;
    constexpr int SAOFF = (UST == 128) ? 64 : 0;
    constexpr int NB = 256 / O;
    constexpr int BPG = 8 / NB;
    int n = blockIdx.x, tid = threadIdx.x;
    int o = tid % O, bg = tid / O;
    __shared__ float xg[2 * I][12];
    for (int idx = tid; idx < 8 * 2 * I; idx += 256) {
        int b = idx / (2 * I), j = idx % (2 * I);
        int kk = (j < I) ? 0 : 1, jj = j - kk * I;
        float v;
        if (YX && jj < 2) {
            v = y0x[(((size_t)(t * B_ + b) * 2 + kk) * N_ + n) * 2 + jj];
        } else {
            int c = jj - JX;
            const float* yp = &ybuf[(((size_t)b * 2 + kk) * N_ + n) * COLS + c];
            v = yp[0];
            for (int s = 1; s < MS_; s++) v += yp[(size_t)s * slotSS];
        }
        xg[j][b] = v;
    }
    __syncthreads();
    float bias = Bb[(size_t)n * O + o];
    float acc[BPG];
#pragma unroll
    for (int q = 0; q < BPG; ++q) acc[q] = bias;
    const float* Wn = W + ((size_t)n * 2 * I) * O + o;
#pragma unroll 4
    for (int j = 0; j < 2 * I; ++j) {
        float w = Wn[(size_t)j * O];
        if (BPG == 4) {
            float4 xb = *(const float4*)&xg[j][bg * 4];
            acc[0] = fmaf(xb.x, w, acc[0]); acc[1] = fmaf(xb.y, w, acc[1]);
            acc[2] = fmaf(xb.z, w, acc[2]); acc[3] = fmaf(xb.w, w, acc[3]);
        } else {
            float2 xb = *(const float2*)&xg[j][bg * 2];
            acc[0] = fmaf(xb.x, w, acc[0]); acc[1] = fmaf(xb.y, w, acc[1]);
        }
    }
#pragma unroll
    for (int q = 0; q < BPG; ++q) {
        int b = bg * BPG + q;
        size_t bn = (size_t)b * N_ + n;
        if (MODE == 0) {
            float v = 1.f / (1.f + __expf(-acc[q]));
            if (o < H_) u2[bn * UST + SAOFF + o] = v * u1[bn * UST + SAOFF + o];
            else        rbuf[bn * H_ + (o - H_)] = v;
            if (!YX && o < 64) u2[bn * 128 + o] = xin[(((size_t)b * T_ + t) * N_ + n) * 64 + o];
        } else {
            float hc = tanhf(acc[q]);
            float r = rbuf[bn * H_ + o];
            float s = u1[bn * UST + SAOFF + o];
            float ns = hc + r * (s - hc);
            seqout[(((size_t)b * T_ + t) * N_ + n) * 64 + o] = ns;
            if (t < T_ - 1) {
                u1[bn * UST + SAOFF + o] = ns + pa[(((size_t)b * T_ + (t + 1)) * N_ + n) * 64 + o];
                if (!YX) u1[bn * 128 + o] = xin[(((size_t)b * T_ + (t + 1)) * N_ + n) * 64 + o];
            } else {
                hidout[bn * H_ + o] = ns;
            }
        }
    }
}

extern "C" void kernel_launch(void* const* d_in, const int* in_sizes, int n_in,
                              void* d_out, int out_size, void* d_ws, size_t ws_size,
                              hipStream_t stream) {
    const float* x   = (const float*)d_in[0];
    const float* ist = (const float*)d_in[1];
    const float* ne  = (const float*)d_in[2];
    const float* pa  = (const float*)d_in[3];
    const float* gw0 = (const float*)d_in[4];
    const float* gb0 = (const float*)d_in[5];
    const float* uw0 = (const float*)d_in[6];
    const float* ub0 = (const float*)d_in[7];
    const float* gw1 = (const float*)d_in[8];
    const float* gb1 = (const float*)d_in[9];
    const float* uw1 = (const float*)d_in[10];
    const float* ub1 = (const float*)d_in[11];
    float* out = (float*)d_out;
    char*  base = (char*)d_ws;

    size_t off = 0;
    auto carve = [&](size_t bytes) { char* p = base + off; off += (bytes + 255) & ~(size_t)255; return p; };
    float* adjw = (float*)carve(65536ull * 4);
    float* Ebuf = (float*)carve(6291456ull * 4);
    float* inv  = (float*)carve(24576ull * 4);
    float* Wg   = (float*)carve(8388608ull * 4);
    float* Wu   = (float*)carve(4194304ull * 4);
    float* Bg0  = (float*)carve(32768ull * 4);
    float* Bu0  = (float*)carve(16384ull * 4);
    float* Bg1  = (float*)carve(32768ull * 4);
    float* Bu1  = (float*)carve(16384ull * 4);
    float* u1   = (float*)carve(262144ull * 4);
    float* u2   = (float*)carve(262144ull * 4);
    float* rbuf = (float*)carve(131072ull * 4);
    float* y0x  = (float*)carve(98304ull * 4);
    float* ybuf = (float*)carve((size_t)MS_ * 524288ull * 4);
    size_t serial_end = off;
    float* A2   = (float*)carve(6291456ull * 4);
    bool useA2 = (off <= ws_size);
    if (serial_end > ws_size) { k_sentinel<<<1, 1, 0, stream>>>(out); return; }

    float* cur_out = out;                                   // (B,T,N,H)
    float* hid_out = out + (size_t)B_ * T_ * N_ * H_;       // (2,B,N,H)
    float* cur0    = cur_out;

    // ---- time-invariant precompute ----
    k_adj<<<256, 256, 0, stream>>>(ne, adjw);
    k_sub_t<<<dim3(16, 96), 256, 0, stream>>>(pa, Ebuf);
    k_csum<<<96, 256, 0, stream>>>(Ebuf, inv);
    if (useA2) {
        k_y<64, 256, 32, 8, false, false><<<dim3(4, 96, 1), 256, 0, stream>>>(
            adjw, adjw, 0L, Ebuf, 65536L, inv, A2, 65536L, 0L, 0, 0);
        k_y0xa<<<dim3(96, 2), 256, 0, stream>>>(Ebuf, A2, inv, x, y0x, 1);
    } else {
        k_y0xa<<<dim3(96, 1), 256, 0, stream>>>(Ebuf, Ebuf, inv, x, y0x, 0);
        k_y0xb<<<96, 256, 0, stream>>>(adjw, y0x);
    }
    k_bias<128><<<256, 128, 0, stream>>>(ne, gb0, Bg0);
    k_bias<64><<<256, 64, 0, stream>>>(ne, ub0, Bu0);
    k_bias<128><<<256, 128, 0, stream>>>(ne, gb1, Bg1);
    k_bias<64><<<256, 64, 0, stream>>>(ne, ub1, Bu1);

    for (int l = 0; l < 2; l++) {
        if (l == 0) {
            int t4g = N_ * 132 * 128 / 4, t4u = N_ * 132 * 64 / 4;
            k_wpool<<<(t4g + 255) / 256, 256, 0, stream>>>(ne, gw0, Wg, 132, 32, t4g);
            k_wpool<<<(t4u + 255) / 256, 256, 0, stream>>>(ne, uw0, Wu, 132, 16, t4u);
            k_init0<<<512, 256, 0, stream>>>(ist, pa, u1);
        } else {
            int t4g = N_ * 256 * 128 / 4, t4u = N_ * 256 * 64 / 4;
            k_wpool<<<(t4g + 255) / 256, 256, 0, stream>>>(ne, gw1, Wg, 256, 32, t4g);
            k_wpool<<<(t4u + 255) / 256, 256, 0, stream>>>(ne, uw1, Wu, 256, 16, t4u);
            k_init1<<<1024, 256, 0, stream>>>(cur0, ist + 131072, pa, u1);
        }
        float* seqout = (l == 0) ? cur0 : cur_out;
        float* hout = hid_out + (size_t)l * 131072;
        const float* xin = cur0;   // only used by l1 mm
        for (int t = 0; t < T_; t++) {
            const float* Et  = Ebuf + (size_t)t * B_ * 65536;
            const float* A2t = A2   + (size_t)t * B_ * 65536;
            const float* invt = inv + t * B_ * N_;
            for (int g = 0; g < 2; g++) {           // g=0 gate(u1), g=1 update(u2)
                const float* uin = g ? u2 : u1;
                if (l == 0) {
                    if (useA2) {
                        k_y<128, 64, 32, 1, false, true><<<dim3(2, 16, MS_), 256, 0, stream>>>(
                            Et, A2t, 65536L, uin, 16384L, invt, ybuf, 16384L, 262144L, 1, 0);
                    } else {
                        k_y<128, 64, 32, 1, false, true><<<dim3(2, 8, MS_), 256, 0, stream>>>(
                            Et, Et, 65536L, uin, 16384L, invt, ybuf, 32768L, 262144L, 0, 0);
                        k_y<128, 64, 32, 1, true, false><<<dim3(2, 8, MS_), 256, 0, stream>>>(
                            adjw, adjw, 0L, ybuf, 32768L, invt, ybuf + 16384, 32768L, 262144L, 0, 0);
                    }
                    if (g == 0) k_mm<66, 128, 0, 64, true><<<256, 256, 0, stream>>>(
                        ybuf, 262144L, y0x, Wg, Bg0, u1, u2, rbuf, nullptr, pa, nullptr, nullptr, t);
                    else        k_mm<66, 64, 1, 64, true><<<256, 256, 0, stream>>>(
                        ybuf, 262144L, y0x, Wu, Bu0, u1, u2, rbuf, nullptr, pa, seqout, hout, t);
                } else {
                    if (useA2) {
                        k_y<128, 128, 32, 1, false, true><<<dim3(2, 16, MS_), 256, 0, stream>>>(
                            Et, A2t, 65536L, uin, 32768L, invt, ybuf, 32768L, 524288L, 1, 0);
                    } else {
                        k_y<128, 128, 32, 1, false, true><<<dim3(2, 8, MS_), 256, 0, stream>>>(
                            Et, Et, 65536L, uin, 32768L, invt, ybuf, 65536L, 524288L, 0, 0);
                        k_y<128, 128, 32, 1, true, false><<<dim3(2, 8, MS_), 256, 0, stream>>>(
                            adjw, adjw, 0L, ybuf, 65536L, invt, ybuf + 32768, 65536L, 524288L, 0, 0);
                    }
                    if (g == 0) k_mm<128, 128, 0, 128, false><<<256, 256, 0, stream>>>(
                        ybuf, 524288L, y0x, Wg, Bg1, u1, u2, rbuf, xin, pa, nullptr, nullptr, t);
                    else        k_mm<128, 64, 1, 128, false><<<256, 256, 0, stream>>>(
                        ybuf, 524288L, y0x, Wu, Bu1, u1, u2, rbuf, xin, pa, seqout, hout, t);
                }
            }
        }
    }
    (void)in_sizes; (void)n_in; (void)out_size;
}